// Round 11
// baseline (339.566 us; speedup 1.0000x reference)
//
#include <hip/hip_runtime.h>
#include <math.h>

// Problem constants (from setup_inputs): B=4 batches
#define NBATCH 4
#define NF 8192   // fine points
#define NC 1024   // coarse points
#define NT 8192   // target points

#define THREADS 256
#define GRID 2304

// Min-array segments (uint bit-patterns of nonneg floats; uint-min == float-min)
#define SEG0 0                  // fine   vs target (NBATCH*NF)
#define SEG1 (NBATCH*NF)        // target vs fine   (NBATCH*NT)
#define SEG2 (SEG1 + NBATCH*NT) // coarse vs target (NBATCH*NC)
#define SEG3 (SEG2 + NBATCH*NC) // target vs coarse (NBATCH*NT)
#define TOTMIN (SEG3 + NBATCH*NT)   // 102400 uints = 400 KB

// ws byte offsets
#define MINS_OFF 0u
#define CNT_OFF  409600u   // 1 uint ticket counter
#define PKT_OFF  410624u   // packed target: 16384 pairs * 32B = 524288
#define PKF_OFF  934912u   // packed fine:   16384 pairs * 32B = 524288
#define PKC_OFF  1459200u  // packed coarse:  2048 pairs * 32B =  65536

typedef float v2f __attribute__((ext_vector_type(2)));
typedef float v8f __attribute__((ext_vector_type(8)));

// d = a * b_s + c ; b_s stays in SGPRs (one SGPR-pair read per instr — legal).
__device__ __forceinline__ v2f pk_fma_sv(v2f a, v2f bs, v2f c) {
    v2f d;
    asm("v_pk_fma_f32 %0, %1, %2, %3" : "=v"(d) : "v"(a), "s"(bs), "v"(c));
    return d;
}
// Single-instruction 3-input min (folds both packed halves + running min).
__device__ __forceinline__ float min3f(float a, float b, float c) {
    float d;
    asm("v_min3_f32 %0, %1, %2, %3" : "=v"(d) : "v"(a), "v"(b), "v"(c));
    return d;
}

// prep: (a) pack B-arrays into pre-paired SoA {x0,x1,y0,y1}{z0,z1,w0,w1} per pair,
//       (b) init mins to +inf, (c) zero the ticket counter.
__global__ __launch_bounds__(256) void prep(const float* __restrict__ fine,
                                            const float* __restrict__ coarse,
                                            const float* __restrict__ tgt,
                                            char* __restrict__ ws) {
    const int bid = blockIdx.x, tid = threadIdx.x;
    if (bid < 136) {   // pack: 64 blocks target, 64 fine, 8 coarse (1 pair/thread)
        const float* src; float4* dst; int p, npairs;
        if (bid < 64)       { src = tgt;    dst = (float4*)(ws + PKT_OFF); p = bid * 256;         npairs = 16384; }
        else if (bid < 128) { src = fine;   dst = (float4*)(ws + PKF_OFF); p = (bid - 64) * 256;  npairs = 16384; }
        else                { src = coarse; dst = (float4*)(ws + PKC_OFF); p = (bid - 128) * 256; npairs = 2048;  }
        p += tid;
        if (p < npairs) {   // batches contiguous & even-sized: flat pairing is safe
            const float* s = src + (size_t)p * 6;
            float x0 = s[0], y0 = s[1], z0 = s[2], x1 = s[3], y1 = s[4], z1 = s[5];
            dst[2 * p]     = make_float4(x0, x1, y0, y1);
            dst[2 * p + 1] = make_float4(z0, z1,
                                         x0 * x0 + y0 * y0 + z0 * z0,
                                         x1 * x1 + y1 * y1 + z1 * z1);
        }
    } else {           // init: 100 blocks * 256 threads * uint4 = 102400 uints
        const int b = bid - 136;
        uint4* m = (uint4*)(ws + MINS_OFF);
        m[b * 256 + tid] = make_uint4(0x7F800000u, 0x7F800000u, 0x7F800000u, 0x7F800000u);
        if (b == 0 && tid == 0) *(unsigned int*)(ws + CNT_OFF) = 0u;
    }
}

// One work unit: K A-points/thread vs NG groups (2 packed B-points each) via SMEM,
// with an explicit 4-deep s_load prefetch pipeline (SGPR rotation, SSA-renamed).
template<int K, int NG>
__device__ __forceinline__ void chamfer_unit(const float* __restrict__ Ab,
                                             const char* __restrict__ pcbase,
                                             unsigned int* __restrict__ minsB,
                                             int a0) {
    typedef __attribute__((address_space(4))) const v8f cv8f;
    cv8f* pc = (cv8f*)(unsigned long long)pcbase;   // constant AS -> s_load

    v2f nx[K], ny[K], nz[K];
    float a2[K], m[K];
#pragma unroll
    for (int k = 0; k < K; ++k) {
        const float* ap = Ab + (size_t)(a0 + k * THREADS) * 3;
        float ax = ap[0], ay = ap[1], az = ap[2];
        nx[k] = (v2f){-2.0f * ax, -2.0f * ax};
        ny[k] = (v2f){-2.0f * ay, -2.0f * ay};
        nz[k] = (v2f){-2.0f * az, -2.0f * az};
        a2[k] = ax * ax + ay * ay + az * az;
        m[k]  = INFINITY;
    }

    auto compute = [&](v8f B) {
        const v2f bx = {B[0], B[1]};
        const v2f by = {B[2], B[3]};
        const v2f bz = {B[4], B[5]};
        const v2f bw = {B[6], B[7]};  // "v" use -> one 2-mov copy per group
#pragma unroll
        for (int k = 0; k < K; ++k) {
            v2f t = pk_fma_sv(nz[k], bz, bw);   // |b|^2 - 2 a.b  (a2 deferred; min-monotone)
            t = pk_fma_sv(ny[k], by, t);
            t = pk_fma_sv(nx[k], bx, t);
            m[k] = min3f(t.x, t.y, m[k]);
        }
    };

    v8f B[4];
#pragma unroll
    for (int u = 0; u < 4; ++u) B[u] = pc[u];
#pragma unroll 1
    for (int g = 0; g < NG - 4; g += 4) {
#pragma unroll
        for (int u = 0; u < 4; ++u) {
            v8f Bc = B[u];
            B[u] = pc[g + 4 + u];   // prefetch 4 groups ahead (stays in flight)
            compute(Bc);
        }
    }
#pragma unroll
    for (int u = 0; u < 4; ++u) compute(B[u]);   // drain last 4 groups

#pragma unroll
    for (int k = 0; k < K; ++k) {
        float sq = fmaxf(a2[k] + m[k], 0.0f);   // >=0 -> uint bits monotone
        atomicMin(&minsB[a0 + k * THREADS], __float_as_uint(sq));
    }
}

// 2304 identical-cost blocks (9.00/CU, 36 waves/CU), 512 fma-triples each:
//   [   0,1024): fine   vs target  K=8 NG=64  (A-chunk 2048, B-chunk 128)
//   [1024,2048): target vs fine    K=8 NG=64
//   [2048,2176): coarse vs target  K=4 NG=128 (A-chunk 1024, B-chunk 256)
//   [2176,2304): target vs coarse  K=8 NG=64
// The LAST block to finish (ticket counter) does the weighted sqrt-sum reduce.
__global__ __launch_bounds__(256) void chamfer_min(const float* __restrict__ fine,
                                                   const float* __restrict__ coarse,
                                                   const float* __restrict__ tgt,
                                                   char* __restrict__ ws,
                                                   float* __restrict__ out) {
    unsigned int* mins = (unsigned int*)(ws + MINS_OFF);
    const int bid = blockIdx.x, tid = threadIdx.x;

    if (bid < 2048) {          // dir0 / dir1
        const int dir = bid >> 10;           // 0 or 1
        const int s   = bid & 1023;
        const int batch = s >> 8;            // 256 units/batch = 4 ach * 64 bch
        const int r = s & 255;
        const int ach = r >> 6, bch = r & 63;
        const float* A  = dir ? tgt : fine;
        const size_t pk = dir ? PKF_OFF : PKT_OFF;
        const int seg   = dir ? SEG1 : SEG0;
        const float* Ab = A + (size_t)batch * NF * 3;          // NF == NT == 8192
        const char* pcb = ws + pk + (size_t)batch * NT * 16 + (size_t)bch * 2048;
        chamfer_unit<8, 64>(Ab, pcb, mins + seg + batch * NF, ach * 2048 + tid);
    } else if (bid < 2176) {   // dir2: coarse vs target (128 blocks)
        const int s = bid - 2048;
        const int batch = s >> 5, bch = s & 31;
        const float* Ab = coarse + (size_t)batch * NC * 3;
        const char* pcb = ws + PKT_OFF + (size_t)batch * NT * 16 + (size_t)bch * 4096;
        chamfer_unit<4, 128>(Ab, pcb, mins + SEG2 + batch * NC, tid);
    } else {                   // dir3: target vs coarse (128 blocks)
        const int s = bid - 2176;
        const int batch = s >> 5;
        const int r = s & 31;
        const int ach = r >> 3, bch = r & 7;
        const float* Ab = tgt + (size_t)batch * NT * 3;
        const char* pcb = ws + PKC_OFF + (size_t)batch * NC * 16 + (size_t)bch * 2048;
        chamfer_unit<8, 64>(Ab, pcb, mins + SEG3 + batch * NT, ach * 2048 + tid);
    }

    // -------- fused finalize: last block to finish reduces everything --------
    __threadfence();                         // my atomicMins acked to coherent point
    __shared__ unsigned int ticket;
    __shared__ double red[256];
    unsigned int* cnt = (unsigned int*)(ws + CNT_OFF);
    __syncthreads();                         // all lanes' atomics issued+drained
    if (tid == 0) ticket = atomicAdd(cnt, 1u);
    __syncthreads();
    if (ticket != GRID - 1) return;

    __threadfence();                         // acquire: see all blocks' mins
    const float wf  = 1.0f / (NBATCH * NF);   // fine row-mins
    const float wt1 = 1.0f / (NBATCH * NT);   // target-vs-fine
    const float wc  = 0.5f / (NBATCH * NC);   // coarse row-mins (ALPHA=0.5)
    const float wt3 = 0.5f / (NBATCH * NT);   // target-vs-coarse

    double acc = 0.0;
    for (int i = tid; i < TOTMIN; i += 256) {  // fixed per-thread order: deterministic
        unsigned int v = __hip_atomic_load(&mins[i], __ATOMIC_RELAXED,
                                           __HIP_MEMORY_SCOPE_AGENT);  // coherent read
        float w = (i < SEG1) ? wf : (i < SEG2) ? wt1 : (i < SEG3) ? wc : wt3;
        acc += (double)(w * sqrtf(__uint_as_float(v)));
    }
    red[tid] = acc;
    __syncthreads();
    for (int s = 128; s > 0; s >>= 1) {
        if (tid < s) red[tid] += red[tid + s];
        __syncthreads();
    }
    if (tid == 0) out[0] = (float)red[0];
}

extern "C" void kernel_launch(void* const* d_in, const int* in_sizes, int n_in,
                              void* d_out, int out_size, void* d_ws, size_t ws_size,
                              hipStream_t stream) {
    const float* fine   = (const float*)d_in[0];
    const float* coarse = (const float*)d_in[1];
    const float* tgt    = (const float*)d_in[2];
    char* ws            = (char*)d_ws;
    float* out          = (float*)d_out;

    hipLaunchKernelGGL(prep,        dim3(236),  dim3(256), 0, stream, fine, coarse, tgt, ws);
    hipLaunchKernelGGL(chamfer_min, dim3(GRID), dim3(256), 0, stream, fine, coarse, tgt, ws, out);
}

// Round 13
// 337.828 us; speedup vs baseline: 1.0051x; 1.0051x over previous
//
#include <hip/hip_runtime.h>
#include <math.h>

// Problem constants (from setup_inputs): B=4 batches
#define NBATCH 4
#define NF 8192   // fine points
#define NC 1024   // coarse points
#define NT 8192   // target points

#define THREADS 256
#define GRID 2304

// Min-array segments (uint bit-patterns of nonneg floats; uint-min == float-min)
#define SEG0 0                  // fine   vs target (NBATCH*NF)
#define SEG1 (NBATCH*NF)        // target vs fine   (NBATCH*NT)
#define SEG2 (SEG1 + NBATCH*NT) // coarse vs target (NBATCH*NC)
#define SEG3 (SEG2 + NBATCH*NC) // target vs coarse (NBATCH*NT)
#define TOTMIN (SEG3 + NBATCH*NT)   // 102400 uints = 400 KB

// ws byte offsets
#define MINS_OFF 0u
#define CNT_OFF  409600u   // 1 uint ticket counter
#define PKT_OFF  410624u   // packed target: 16384 pairs * 32B = 524288
#define PKF_OFF  934912u   // packed fine:   16384 pairs * 32B = 524288
#define PKC_OFF  1459200u  // packed coarse:  2048 pairs * 32B =  65536

typedef float v2f __attribute__((ext_vector_type(2)));
typedef float v8f __attribute__((ext_vector_type(8)));

// d = a * b_s + c ; b_s stays in SGPRs (one SGPR-pair read per instr — legal).
// NOTE: the "s" operand must be fed DIRECTLY from the addrspace(4) load
// expression — staging loads in arrays across iterations breaks the
// compiler's uniformity proof (round-11 regression: 50->303 us).
__device__ __forceinline__ v2f pk_fma_sv(v2f a, v2f bs, v2f c) {
    v2f d;
    asm("v_pk_fma_f32 %0, %1, %2, %3" : "=v"(d) : "v"(a), "s"(bs), "v"(c));
    return d;
}
// Single-instruction 3-input min (folds both packed halves + running min).
__device__ __forceinline__ float min3f(float a, float b, float c) {
    float d;
    asm("v_min3_f32 %0, %1, %2, %3" : "=v"(d) : "v"(a), "v"(b), "v"(c));
    return d;
}

// prep: (a) pack B-arrays into pre-paired SoA {x0,x1,y0,y1}{z0,z1,w0,w1} per pair,
//       (b) init mins to +inf, (c) zero the ticket counter.
__global__ __launch_bounds__(256) void prep(const float* __restrict__ fine,
                                            const float* __restrict__ coarse,
                                            const float* __restrict__ tgt,
                                            char* __restrict__ ws) {
    const int bid = blockIdx.x, tid = threadIdx.x;
    if (bid < 136) {   // pack: 64 blocks target, 64 fine, 8 coarse (1 pair/thread)
        const float* src; float4* dst; int p, npairs;
        if (bid < 64)       { src = tgt;    dst = (float4*)(ws + PKT_OFF); p = bid * 256;         npairs = 16384; }
        else if (bid < 128) { src = fine;   dst = (float4*)(ws + PKF_OFF); p = (bid - 64) * 256;  npairs = 16384; }
        else                { src = coarse; dst = (float4*)(ws + PKC_OFF); p = (bid - 128) * 256; npairs = 2048;  }
        p += tid;
        if (p < npairs) {   // batches contiguous & even-sized: flat pairing is safe
            const float* s = src + (size_t)p * 6;
            float x0 = s[0], y0 = s[1], z0 = s[2], x1 = s[3], y1 = s[4], z1 = s[5];
            dst[2 * p]     = make_float4(x0, x1, y0, y1);
            dst[2 * p + 1] = make_float4(z0, z1,
                                         x0 * x0 + y0 * y0 + z0 * z0,
                                         x1 * x1 + y1 * y1 + z1 * z1);
        }
    } else {           // init: 100 blocks * 256 threads * uint4 = 102400 uints
        const int b = bid - 136;
        uint4* m = (uint4*)(ws + MINS_OFF);
        m[b * 256 + tid] = make_uint4(0x7F800000u, 0x7F800000u, 0x7F800000u, 0x7F800000u);
        if (b == 0 && tid == 0) *(unsigned int*)(ws + CNT_OFF) = 0u;
    }
}

// One work unit: K A-points/thread vs NG groups (2 packed B-points each) via SMEM.
// Per group: 1 s_load_dwordx8 (scalar pipe) + K*(3 pk_fma + 1 min3) VALU.
// Unroll 8: batch 8 s_loads per lgkmcnt drain to amortize SMEM latency.
template<int K, int NG>
__device__ __forceinline__ void chamfer_unit(const float* __restrict__ Ab,
                                             const char* __restrict__ pcbase,
                                             unsigned int* __restrict__ minsB,
                                             int a0) {
    typedef __attribute__((address_space(4))) const v8f cv8f;
    cv8f* pc = (cv8f*)(unsigned long long)pcbase;   // constant AS -> s_load

    v2f nx[K], ny[K], nz[K];
    float a2[K], m[K];
#pragma unroll
    for (int k = 0; k < K; ++k) {
        const float* ap = Ab + (size_t)(a0 + k * THREADS) * 3;
        float ax = ap[0], ay = ap[1], az = ap[2];
        nx[k] = (v2f){-2.0f * ax, -2.0f * ax};
        ny[k] = (v2f){-2.0f * ay, -2.0f * ay};
        nz[k] = (v2f){-2.0f * az, -2.0f * az};
        a2[k] = ax * ax + ay * ay + az * az;
        m[k]  = INFINITY;
    }

#pragma unroll 8
    for (int g = 0; g < NG; ++g) {
        const v8f B = pc[g];          // s_load, fed straight into the asm below
        const v2f bx = {B[0], B[1]};
        const v2f by = {B[2], B[3]};
        const v2f bz = {B[4], B[5]};
        const v2f bw = {B[6], B[7]};  // "v" use below -> one 2-mov copy per group
#pragma unroll
        for (int k = 0; k < K; ++k) {
            v2f t = pk_fma_sv(nz[k], bz, bw);   // |b|^2 - 2 a.b  (a2 deferred; min-monotone)
            t = pk_fma_sv(ny[k], by, t);
            t = pk_fma_sv(nx[k], bx, t);
            m[k] = min3f(t.x, t.y, m[k]);
        }
    }

#pragma unroll
    for (int k = 0; k < K; ++k) {
        float sq = fmaxf(a2[k] + m[k], 0.0f);   // >=0 -> uint bits monotone
        atomicMin(&minsB[a0 + k * THREADS], __float_as_uint(sq));
    }
}

// 2304 identical-cost blocks (9.00/CU, 36 waves/CU), 512 fma-triples each:
//   [   0,1024): fine   vs target  K=4 NG=128 (A-chunk 1024, B-chunk 256 pts)
//   [1024,2048): target vs fine    K=4 NG=128
//   [2048,2176): coarse vs target  K=4 NG=128
//   [2176,2304): target vs coarse  K=4 NG=128
// The LAST block to finish (ticket counter) does the weighted sqrt-sum reduce.
__global__ __launch_bounds__(256) void chamfer_min(const float* __restrict__ fine,
                                                   const float* __restrict__ coarse,
                                                   const float* __restrict__ tgt,
                                                   char* __restrict__ ws,
                                                   float* __restrict__ out) {
    unsigned int* mins = (unsigned int*)(ws + MINS_OFF);
    const int bid = blockIdx.x, tid = threadIdx.x;

    if (bid < 2048) {          // dir0 / dir1
        const int dir = bid >> 10;           // 0 or 1
        const int s   = bid & 1023;
        const int batch = s >> 8;            // 256 units/batch = 8 ach * 32 bch
        const int r = s & 255;
        const int ach = r >> 5, bch = r & 31;
        const float* A  = dir ? tgt : fine;
        const size_t pk = dir ? PKF_OFF : PKT_OFF;
        const int seg   = dir ? SEG1 : SEG0;
        const float* Ab = A + (size_t)batch * NF * 3;          // NF == NT == 8192
        const char* pcb = ws + pk + (size_t)batch * NT * 16 + (size_t)bch * 4096;
        chamfer_unit<4, 128>(Ab, pcb, mins + seg + batch * NF, ach * 1024 + tid);
    } else if (bid < 2176) {   // dir2: coarse vs target (128 blocks)
        const int s = bid - 2048;
        const int batch = s >> 5, bch = s & 31;
        const float* Ab = coarse + (size_t)batch * NC * 3;
        const char* pcb = ws + PKT_OFF + (size_t)batch * NT * 16 + (size_t)bch * 4096;
        chamfer_unit<4, 128>(Ab, pcb, mins + SEG2 + batch * NC, tid);
    } else {                   // dir3: target vs coarse (128 blocks)
        const int s = bid - 2176;
        const int batch = s >> 5;
        const int r = s & 31;
        const int ach = r >> 2, bch = r & 3;
        const float* Ab = tgt + (size_t)batch * NT * 3;
        const char* pcb = ws + PKC_OFF + (size_t)batch * NC * 16 + (size_t)bch * 4096;
        chamfer_unit<4, 128>(Ab, pcb, mins + SEG3 + batch * NT, ach * 1024 + tid);
    }

    // -------- fused finalize: last block to finish reduces everything --------
    __threadfence();                         // my atomicMins acked to coherent point
    __shared__ unsigned int ticket;
    __shared__ double red[256];
    unsigned int* cnt = (unsigned int*)(ws + CNT_OFF);
    __syncthreads();                         // all lanes' atomics issued+drained
    if (tid == 0) ticket = atomicAdd(cnt, 1u);
    __syncthreads();
    if (ticket != GRID - 1) return;

    __threadfence();                         // acquire: see all blocks' mins
    const float wf  = 1.0f / (NBATCH * NF);   // fine row-mins
    const float wt1 = 1.0f / (NBATCH * NT);   // target-vs-fine
    const float wc  = 0.5f / (NBATCH * NC);   // coarse row-mins (ALPHA=0.5)
    const float wt3 = 0.5f / (NBATCH * NT);   // target-vs-coarse

    double acc = 0.0;
    for (int i = tid; i < TOTMIN; i += 256) {  // fixed per-thread order: deterministic
        unsigned int v = __hip_atomic_load(&mins[i], __ATOMIC_RELAXED,
                                           __HIP_MEMORY_SCOPE_AGENT);  // coherent read
        float w = (i < SEG1) ? wf : (i < SEG2) ? wt1 : (i < SEG3) ? wc : wt3;
        acc += (double)(w * sqrtf(__uint_as_float(v)));
    }
    red[tid] = acc;
    __syncthreads();
    for (int s = 128; s > 0; s >>= 1) {
        if (tid < s) red[tid] += red[tid + s];
        __syncthreads();
    }
    if (tid == 0) out[0] = (float)red[0];
}

extern "C" void kernel_launch(void* const* d_in, const int* in_sizes, int n_in,
                              void* d_out, int out_size, void* d_ws, size_t ws_size,
                              hipStream_t stream) {
    const float* fine   = (const float*)d_in[0];
    const float* coarse = (const float*)d_in[1];
    const float* tgt    = (const float*)d_in[2];
    char* ws            = (char*)d_ws;
    float* out          = (float*)d_out;

    hipLaunchKernelGGL(prep,        dim3(236),  dim3(256), 0, stream, fine, coarse, tgt, ws);
    hipLaunchKernelGGL(chamfer_min, dim3(GRID), dim3(256), 0, stream, fine, coarse, tgt, ws, out);
}

// Round 16
// 106.127 us; speedup vs baseline: 3.1996x; 3.1832x over previous
//
#include <hip/hip_runtime.h>
#include <math.h>

// Problem constants (from setup_inputs): B=4 batches
#define NBATCH 4
#define NF 8192   // fine points
#define NC 1024   // coarse points
#define NT 8192   // target points

// Min-array segments (uint bit-patterns of nonneg floats; uint-min == float-min)
#define SEG0 0                  // fine   vs target (NBATCH*NF)
#define SEG1 (NBATCH*NF)        // target vs fine   (NBATCH*NT)
#define SEG2 (SEG1 + NBATCH*NT) // coarse vs target (NBATCH*NC)
#define SEG3 (SEG2 + NBATCH*NC) // target vs coarse (NBATCH*NT)
#define TOTMIN (SEG3 + NBATCH*NT)   // 102400 uints = 400 KB

// ws byte offsets
#define MINS_OFF 0u
#define PART_OFF 409600u   // 64 doubles (8-aligned)
#define CNT_OFF  410112u   // 1 uint ticket counter
#define PKT_OFF  410624u   // packed target: 16384 pairs * 32B = 524288
#define PKF_OFF  934912u   // packed fine:   16384 pairs * 32B = 524288
#define PKC_OFF  1459200u  // packed coarse:  2048 pairs * 32B =  65536

#define RBLOCKS 64

// LESSON (r11/r13, both ~300us @ VALUBusy 11%): do NOT fuse a finalize that
// makes every block execute __threadfence() — the agent-scope fence emits
// buffer_wbl2/buffer_inv (L2 writeback + K$/L1 invalidate) per wave, and
// ~9216 of them thrash the scalar-cache path the s_load B-reads depend on.
// Keep the reduce as a SEPARATE kernel (64 fences total — measured harmless).

typedef float v2f __attribute__((ext_vector_type(2)));
typedef float v8f __attribute__((ext_vector_type(8)));

// d = a * b_s + c ; b_s stays in SGPRs (one SGPR-pair read per instr — legal).
// The "s" operand must be fed DIRECTLY from the addrspace(4) load expression.
__device__ __forceinline__ v2f pk_fma_sv(v2f a, v2f bs, v2f c) {
    v2f d;
    asm("v_pk_fma_f32 %0, %1, %2, %3" : "=v"(d) : "v"(a), "s"(bs), "v"(c));
    return d;
}
// Single-instruction 3-input min (folds both packed halves + running min).
__device__ __forceinline__ float min3f(float a, float b, float c) {
    float d;
    asm("v_min3_f32 %0, %1, %2, %3" : "=v"(d) : "v"(a), "v"(b), "v"(c));
    return d;
}

// prep: (a) pack B-arrays into pre-paired SoA {x0,x1,y0,y1}{z0,z1,w0,w1} per pair,
//       (b) init mins to +inf, (c) zero the reduce ticket counter.
__global__ __launch_bounds__(256) void prep(const float* __restrict__ fine,
                                            const float* __restrict__ coarse,
                                            const float* __restrict__ tgt,
                                            char* __restrict__ ws) {
    const int bid = blockIdx.x, tid = threadIdx.x;
    if (bid < 136) {   // pack: 64 blocks target, 64 fine, 8 coarse (1 pair/thread)
        const float* src; float4* dst; int p, npairs;
        if (bid < 64)       { src = tgt;    dst = (float4*)(ws + PKT_OFF); p = bid * 256;         npairs = 16384; }
        else if (bid < 128) { src = fine;   dst = (float4*)(ws + PKF_OFF); p = (bid - 64) * 256;  npairs = 16384; }
        else                { src = coarse; dst = (float4*)(ws + PKC_OFF); p = (bid - 128) * 256; npairs = 2048;  }
        p += tid;
        if (p < npairs) {   // batches contiguous & even-sized: flat pairing is safe
            const float* s = src + (size_t)p * 6;
            float x0 = s[0], y0 = s[1], z0 = s[2], x1 = s[3], y1 = s[4], z1 = s[5];
            dst[2 * p]     = make_float4(x0, x1, y0, y1);
            dst[2 * p + 1] = make_float4(z0, z1,
                                         x0 * x0 + y0 * y0 + z0 * z0,
                                         x1 * x1 + y1 * y1 + z1 * z1);
        }
    } else {           // init: 100 blocks * 256 threads * uint4 = 102400 uints
        const int b = bid - 136;
        uint4* m = (uint4*)(ws + MINS_OFF);
        m[b * 256 + tid] = make_uint4(0x7F800000u, 0x7F800000u, 0x7F800000u, 0x7F800000u);
        if (b == 0 && tid == 0) *(unsigned int*)(ws + CNT_OFF) = 0u;
    }
}

// 2304 identical-cost units (9.00/CU): A-chunk=1024 (4 pts/thread), B-chunk=256 pts.
//   [   0,1024): fine   vs target
//   [1024,2048): target vs fine
//   [2048,2176): coarse vs target
//   [2176,2304): target vs coarse
// B-chunk read via s_load (addrspace(4), wave-uniform) -> SMEM pipe, zero VMEM/TA cost.
// Inner: per 32B group (2 B-points), per k: 3 pk_fma (1 SGPR operand) + 1 min3.
__global__ __launch_bounds__(256) void chamfer_min(const float* __restrict__ fine,
                                                   const float* __restrict__ coarse,
                                                   const float* __restrict__ tgt,
                                                   char* __restrict__ ws) {
    unsigned int* mins = (unsigned int*)(ws + MINS_OFF);
    const int bid = blockIdx.x, tid = threadIdx.x;

    const float* A; size_t pkoff; int nA, nB, seg, batch, ach, bch;
    if (bid < 1024)      { int s = bid;        batch = s >> 8; int r = s & 255; ach = r >> 5; bch = r & 31;
                           A = fine;   pkoff = PKT_OFF; nA = NF; nB = NT; seg = SEG0; }
    else if (bid < 2048) { int s = bid - 1024; batch = s >> 8; int r = s & 255; ach = r >> 5; bch = r & 31;
                           A = tgt;    pkoff = PKF_OFF; nA = NT; nB = NF; seg = SEG1; }
    else if (bid < 2176) { int s = bid - 2048; batch = s >> 5; ach = 0;         bch = s & 31;
                           A = coarse; pkoff = PKT_OFF; nA = NC; nB = NT; seg = SEG2; }
    else                 { int s = bid - 2176; batch = s >> 5; int r = s & 31;  ach = r >> 2; bch = r & 3;
                           A = tgt;    pkoff = PKC_OFF; nA = NT; nB = NC; seg = SEG3; }

    const float* Ab = A + (size_t)batch * nA * 3;
    // chunk base: region + batch*(nB pts * 16 B/pt) + bch*(128 pairs * 32 B)
    const size_t cbyte = pkoff + (size_t)batch * nB * 16 + (size_t)bch * 4096;
    typedef __attribute__((address_space(4))) const v8f cv8f;
    cv8f* pc = (cv8f*)(unsigned long long)(ws + cbyte);   // constant AS -> s_load

    const int a0 = ach * 1024 + tid;
    v2f nx[4], ny[4], nz[4];
    float a2[4], m[4];
#pragma unroll
    for (int k = 0; k < 4; ++k) {
        const float* ap = Ab + (size_t)(a0 + k * 256) * 3;
        float ax = ap[0], ay = ap[1], az = ap[2];
        nx[k] = (v2f){-2.0f * ax, -2.0f * ax};
        ny[k] = (v2f){-2.0f * ay, -2.0f * ay};
        nz[k] = (v2f){-2.0f * az, -2.0f * az};
        a2[k] = ax * ax + ay * ay + az * az;
        m[k]  = INFINITY;
    }

#pragma unroll 4
    for (int g = 0; g < 128; ++g) {   // 128 groups x 2 B-points, all via SMEM
        const v8f B = pc[g];          // s_load, fed straight into the asm below
        const v2f bx = {B[0], B[1]};
        const v2f by = {B[2], B[3]};
        const v2f bz = {B[4], B[5]};
        const v2f bw = {B[6], B[7]};  // "v" use below -> one 2-mov copy per group
#pragma unroll
        for (int k = 0; k < 4; ++k) {
            v2f t = pk_fma_sv(nz[k], bz, bw);   // |b|^2 - 2 a.b  (a2 deferred)
            t = pk_fma_sv(ny[k], by, t);
            t = pk_fma_sv(nx[k], bx, t);
            m[k] = min3f(t.x, t.y, m[k]);
        }
    }

#pragma unroll
    for (int k = 0; k < 4; ++k) {
        float sq = fmaxf(a2[k] + m[k], 0.0f);   // >=0 -> uint bits monotone
        atomicMin(&mins[seg + batch * nA + a0 + k * 256], __float_as_uint(sq));
    }
}

// 64 blocks; each reduces a strided slice to a double partial; last block to finish
// (ticket counter, device-scope) folds the 64 partials in fixed order (deterministic).
__global__ __launch_bounds__(256) void chamfer_reduce(char* __restrict__ ws,
                                                      float* __restrict__ out) {
    const unsigned int* mins = (const unsigned int*)(ws + MINS_OFF);
    double* part = (double*)(ws + PART_OFF);
    unsigned int* cnt = (unsigned int*)(ws + CNT_OFF);
    const int tid = threadIdx.x, bid = blockIdx.x;

    const float wf  = 1.0f / (NBATCH * NF);   // fine row-mins
    const float wt1 = 1.0f / (NBATCH * NT);   // target-vs-fine
    const float wc  = 0.5f / (NBATCH * NC);   // coarse row-mins (ALPHA=0.5)
    const float wt3 = 0.5f / (NBATCH * NT);   // target-vs-coarse

    double acc = 0.0;
    for (int i = bid * 256 + tid; i < TOTMIN; i += RBLOCKS * 256) {
        float w = (i < SEG1) ? wf : (i < SEG2) ? wt1 : (i < SEG3) ? wc : wt3;
        acc += (double)(w * sqrtf(__uint_as_float(mins[i])));
    }

    __shared__ double red[256];
    __shared__ unsigned int ticket;
    red[tid] = acc;
    __syncthreads();
    for (int s = 128; s > 0; s >>= 1) {
        if (tid < s) red[tid] += red[tid + s];
        __syncthreads();
    }
    if (tid == 0) {
        part[bid] = red[0];
        __threadfence();                    // release partial before ticket
        ticket = atomicAdd(cnt, 1u);
    }
    __syncthreads();
    if (ticket == RBLOCKS - 1) {            // last block folds
        __threadfence();                    // acquire other blocks' partials
        red[tid] = (tid < RBLOCKS) ? part[tid] : 0.0;
        __syncthreads();
        for (int s = 128; s > 0; s >>= 1) {
            if (tid < s) red[tid] += red[tid + s];
            __syncthreads();
        }
        if (tid == 0) out[0] = (float)red[0];
    }
}

extern "C" void kernel_launch(void* const* d_in, const int* in_sizes, int n_in,
                              void* d_out, int out_size, void* d_ws, size_t ws_size,
                              hipStream_t stream) {
    const float* fine   = (const float*)d_in[0];
    const float* coarse = (const float*)d_in[1];
    const float* tgt    = (const float*)d_in[2];
    char* ws            = (char*)d_ws;
    float* out          = (float*)d_out;

    hipLaunchKernelGGL(prep,           dim3(236),     dim3(256), 0, stream, fine, coarse, tgt, ws);
    hipLaunchKernelGGL(chamfer_min,    dim3(2304),    dim3(256), 0, stream, fine, coarse, tgt, ws);
    hipLaunchKernelGGL(chamfer_reduce, dim3(RBLOCKS), dim3(256), 0, stream, ws, out);
}